// Round 18
// baseline (644.918 us; speedup 1.0000x reference)
//
#include <hip/hip_runtime.h>
#include <stdint.h>

// GATConv fused v19 = v12's 16-wave structure (1024 thr, rg/ch split,
// verified-correct numerics) made spill-free + v14/v18 wins.
// R17: v18 flat (494.7 ~= v14's 494.9) -> residual ~315us is harness-side;
// flash's 179us latency floor (no pipe >30%, 2 waves/SIMD) is the target.
// v12 forensics: FETCH +772MB = ~23 dwords/thread/iter => demand ~151 regs
// vs 128 budget -> ~23 spilled. The misfit is exactly ql[8] (32 VGPR).
// Ql is 4MB, L2-resident, same addresses every tile -> load per-tile into
// TRANSIENT regs (8 VMEM L2 hits/tile/wave, drain under QK's 32 MFMAs on the
// idle VMEM pipe). Peak live ~120-127 < 128 -> no spill -> 4 waves/SIMD.
// Per-CU LDS/MFMA traffic invariant; occupancy 2x. Keeps: DPP reduce (v14),
// PSTR 68 bank-clean P (v14), fused prep (v18), 3-barrier pmax/P/dbuf (v12).

typedef _Float16 f16;
typedef unsigned short u16;
typedef __attribute__((ext_vector_type(8))) _Float16 f16x8;
typedef __attribute__((ext_vector_type(4))) _Float16 f16x4;
typedef __attribute__((ext_vector_type(4))) float f32x4;

#define NN 8192
#define DD 256
#define BR 128
#define BC 64
#define CCH 4
#define COLS (NN / CCH)  // 2048
#define NIT (COLS / BC)  // 32
#define PSTR 68          // P row stride in f16 (136 B: quad phases 0/32/64/96)

#define MFMA(a, b, c) __builtin_amdgcn_mfma_f32_16x16x32_f16((a), (b), (c), 0, 0, 0)

__device__ __forceinline__ void gl2lds16(const void* g, void* l) {
    __builtin_amdgcn_global_load_lds(
        (const __attribute__((address_space(1))) unsigned int*)g,
        (__attribute__((address_space(3))) unsigned int*)l, 16, 0, 0);
}

__device__ __forceinline__ u16 f16bits(f16 h) {
    union { f16 h; u16 u; } c;
    c.h = h;
    return c.u;
}

// 16-lane butterfly reduce on the VALU pipe (DPP) -- validated R4.
__device__ __forceinline__ float dpp_max16(float x) {
    union { float f; int i; } a, b;
    a.f = x;
    b.i = __builtin_amdgcn_mov_dpp(a.i, 0xB1, 0xf, 0xf, true);
    a.f = fmaxf(a.f, b.f);
    b.i = __builtin_amdgcn_mov_dpp(a.i, 0x4E, 0xf, 0xf, true);
    a.f = fmaxf(a.f, b.f);
    b.i = __builtin_amdgcn_mov_dpp(a.i, 0x141, 0xf, 0xf, true);
    a.f = fmaxf(a.f, b.f);
    b.i = __builtin_amdgcn_mov_dpp(a.i, 0x140, 0xf, 0xf, true);
    a.f = fmaxf(a.f, b.f);
    return a.f;
}

__device__ __forceinline__ float dpp_sum16(float x) {
    union { float f; int i; } a, b;
    a.f = x;
    b.i = __builtin_amdgcn_mov_dpp(a.i, 0xB1, 0xf, 0xf, true);
    a.f += b.f;
    b.i = __builtin_amdgcn_mov_dpp(a.i, 0x4E, 0xf, 0xf, true);
    a.f += b.f;
    b.i = __builtin_amdgcn_mov_dpp(a.i, 0x141, 0xf, 0xf, true);
    a.f += b.f;
    b.i = __builtin_amdgcn_mov_dpp(a.i, 0x140, 0xf, 0xf, true);
    a.f += b.f;
    return a.f;
}

// ---------------- fused prep: splitX (blocks 0..2047) + splitW (2048..2815) ----
__global__ __launch_bounds__(256) void prep_kernel(
    const float4* __restrict__ X, f16x4* __restrict__ Xh, f16x4* __restrict__ Xl,
    const float* __restrict__ Wq, const float* __restrict__ Wk,
    const float* __restrict__ Wv, f16* __restrict__ WtH, f16* __restrict__ WtL) {
    const int bid = blockIdx.x;
    if (bid < 2048) {
        const int i = bid * 256 + threadIdx.x;  // 524288
        const float4 v = X[i];
        const f16 h0 = (f16)v.x, h1 = (f16)v.y, h2 = (f16)v.z, h3 = (f16)v.w;
        f16x4 H = {h0, h1, h2, h3};
        f16x4 L = {(f16)(v.x - (float)h0), (f16)(v.y - (float)h1),
                   (f16)(v.z - (float)h2), (f16)(v.w - (float)h3)};
        Xh[i] = H;
        Xl[i] = L;
    } else {
        const int i = (bid - 2048) * 256 + threadIdx.x;  // 3*65536
        const int mat = i >> 16;
        const int k = (i >> 8) & 255;
        const int n = i & 255;
        const float* W = (mat == 0) ? Wq : ((mat == 1) ? Wk : Wv);
        const float v = W[k * 256 + n];
        const f16 h = (f16)v;
        const size_t o = (size_t)(mat * 256 + n) * 256 + k;
        WtH[o] = h;
        WtL[o] = (f16)(v - (float)h);
    }
}

// ---------------- QKV GEMM: LDS-staged W chunks, X frags in registers ----------------
__global__ __launch_bounds__(256, 2) void qkv_kernel(
    const f16* __restrict__ Xh, const f16* __restrict__ Xl,
    const f16* __restrict__ WtH, const f16* __restrict__ WtL,
    f16* __restrict__ Qh, f16* __restrict__ Ql,
    f16* __restrict__ Kh, f16* __restrict__ Vt) {
    __shared__ f16 Wh[64 * 256];
    __shared__ f16 Wl[64 * 256];
    const int lane = threadIdx.x & 63;
    const int w = threadIdx.x >> 6;
    const int l15 = lane & 15;
    const int quad = lane >> 4;
    const int r0 = blockIdx.x * 64;
    const int mat = blockIdx.y;

    f16x8 xh[8], xl[8];
    const size_t xb = (size_t)(r0 + w * 16 + l15) * DD + quad * 8;
#pragma unroll
    for (int kc = 0; kc < 8; ++kc) {
        xh[kc] = *(const f16x8*)(Xh + xb + kc * 32);
        xl[kc] = *(const f16x8*)(Xl + xb + kc * 32);
    }
    const int orow = r0 + w * 16 + quad * 4;

#pragma unroll 1
    for (int c = 0; c < 4; ++c) {
        const int nb = mat * 256 + c * 64;
#pragma unroll
        for (int i = 0; i < 8; ++i) {
            const int r = w * 16 + i * 2 + (lane >> 5);
            gl2lds16(WtH + (size_t)(nb + r) * DD + (((lane & 31) ^ (r & 7)) * 8),
                     &Wh[(w * 16 + i * 2) * 256]);
        }
#pragma unroll
        for (int i = 0; i < 8; ++i) {
            const int r = w * 16 + i * 2 + (lane >> 5);
            gl2lds16(WtL + (size_t)(nb + r) * DD + (((lane & 31) ^ (r & 7)) * 8),
                     &Wl[(w * 16 + i * 2) * 256]);
        }
        __syncthreads();

        const f32x4 fzero = {0.f, 0.f, 0.f, 0.f};
        f32x4 acc[4];
#pragma unroll
        for (int nt = 0; nt < 4; ++nt) acc[nt] = fzero;
#pragma unroll
        for (int kc = 0; kc < 8; ++kc)
#pragma unroll
            for (int nt = 0; nt < 4; ++nt) {
                const int r = nt * 16 + l15;
                const int blk = (((kc * 4 + quad) ^ (r & 7)) * 8);
                const f16x8 wh = *(const f16x8*)&Wh[r * 256 + blk];
                const f16x8 wl = *(const f16x8*)&Wl[r * 256 + blk];
                acc[nt] = MFMA(xh[kc], wh, acc[nt]);
                acc[nt] = MFMA(xh[kc], wl, acc[nt]);
                acc[nt] = MFMA(xl[kc], wh, acc[nt]);
            }

        if (mat == 0) {
#pragma unroll
            for (int nt = 0; nt < 4; ++nt)
#pragma unroll
                for (int rg = 0; rg < 4; ++rg) {
                    const int col = c * 64 + nt * 16 + l15;
                    const float v = acc[nt][rg];
                    const f16 h = (f16)v;
                    Qh[(size_t)(orow + rg) * DD + col] = h;
                    Ql[(size_t)(orow + rg) * DD + col] = (f16)(v - (float)h);
                }
        } else if (mat == 1) {
#pragma unroll
            for (int nt = 0; nt < 4; ++nt)
#pragma unroll
                for (int rg = 0; rg < 4; ++rg) {
                    const int col = c * 64 + nt * 16 + l15;
                    Kh[(size_t)(orow + rg) * DD + col] = (f16)acc[nt][rg];
                }
        } else {
#pragma unroll
            for (int nt = 0; nt < 4; ++nt) {
                const int n = c * 64 + nt * 16 + l15;
                ushort4 pk;
                pk.x = f16bits((f16)acc[nt][0]);
                pk.y = f16bits((f16)acc[nt][1]);
                pk.z = f16bits((f16)acc[nt][2]);
                pk.w = f16bits((f16)acc[nt][3]);
                *(ushort4*)(Vt + (size_t)n * NN + orow) = pk;
            }
        }
        __syncthreads();
    }
}

// ---------------- flash kernel v19: 16 waves, ql from L2, DPP, PSTR 68 ----------
// grid 256 linear (1 block/CU): cch = bid&3, rowblk = bid>>2, BR=128.
// wave w: rg = w>>1 (16-row group), ch = w&1 (32-col QK half / 128-n PV half).
__global__ __launch_bounds__(1024, 4) void flash_kernel(
    const f16* __restrict__ Qh, const f16* __restrict__ Ql,
    const f16* __restrict__ Kh, const f16* __restrict__ Vt,
    const int* __restrict__ A,
    float* __restrict__ pO, float* __restrict__ pM, float* __restrict__ pL) {
    __shared__ f16 Klds[2][64 * 256];    // 64 KB dbuf, [j][k] XOR-swizzled by j&7
    __shared__ f16 Vlds[2][256 * 64];    // 64 KB dbuf, [n][j] swizzled by n&7
    __shared__ f16 Plds[8][16 * PSTR];   // 17 KB, per ROW-GROUP, stride 68
    __shared__ float pmaxLds[8][2][16];  // 1 KB, pair max exchange (reused l-sum)

    const int lane = threadIdx.x & 63;
    const int w = threadIdx.x >> 6;  // 0..15
    const int rg = w >> 1;
    const int ch = w & 1;
    const int l15 = lane & 15;
    const int quad = lane >> 4;
    const int bid = blockIdx.x;
    const int cch = bid & 3;
    const int r0 = (bid >> 2) * BR;
    const int col0 = cch * COLS;

    // Q-hi resident (32 VGPR); Q-lo re-read from L2 per tile (transient).
    f16x8 qh[8];
    const size_t qb = (size_t)(r0 + rg * 16 + l15) * DD + quad * 8;
#pragma unroll
    for (int kc = 0; kc < 8; ++kc) qh[kc] = *(const f16x8*)(Qh + qb + kc * 32);

    const f32x4 fzero = {0.f, 0.f, 0.f, 0.f};
    f32x4 accO[8];  // 16 rows x 128 n (ch half)
#pragma unroll
    for (int i = 0; i < 8; ++i) accO[i] = fzero;
    float mrow[4], lpart[4];  // mrow identical across the ch pair by construction
#pragma unroll
    for (int r = 0; r < 4; ++r) {
        mrow[r] = -1e30f;
        lpart[r] = 0.f;
    }
    const int growb = r0 + rg * 16 + quad * 4;
    f16* Pw = &Plds[rg][0];

    // stage tile `t` into buffer `b` (each of 16 waves: 2 K + 2 V gl2lds)
    auto stage = [&](int t, int b) {
        const int j0s = col0 + t * BC;
#pragma unroll
        for (int i = 0; i < 2; ++i) {
            const int r = w * 4 + i * 2 + (lane >> 5);
            gl2lds16(Kh + (size_t)(j0s + r) * DD + (((lane & 31) ^ (r & 7)) * 8),
                     &Klds[b][(w * 4 + i * 2) * 256]);
        }
#pragma unroll
        for (int i = 0; i < 2; ++i) {
            const int n = w * 16 + i * 8 + (lane >> 3);
            gl2lds16(Vt + (size_t)n * NN + j0s + (((lane & 7) ^ (n & 7)) * 8),
                     &Vlds[b][(w * 16 + i * 8) * 64]);
        }
    };

    // prologue: stage tile 0 -> buf 0
    stage(0, 0);
    __syncthreads();

#pragma unroll 1
    for (int it = 0; it < NIT; ++it) {
        const int cur = it & 1;
        const int j0 = col0 + it * BC;

        // stage NEXT tile (drained at the pmax barrier, covered by QK)
        if (it + 1 < NIT) stage(it + 1, cur ^ 1);

        // adjacency for this wave's 32-col half (nontemporal; overlaps QK issue)
        int av[4][2];
#pragma unroll
        for (int rgi = 0; rgi < 4; ++rgi)
#pragma unroll
            for (int jt = 0; jt < 2; ++jt)
                av[rgi][jt] = __builtin_nontemporal_load(
                    A + (size_t)(growb + rgi) * NN + j0 + ch * 32 + jt * 16 + l15);

        // Q-lo transient reload (same addresses every tile -> L1/L2 hits;
        // 8 independent VMEM loads drain under the 32 MFMAs below)
        f16x8 qlt[8];
#pragma unroll
        for (int kc = 0; kc < 8; ++kc) qlt[kc] = *(const f16x8*)(Ql + qb + kc * 32);

        // S = (Qh+Ql)·Kh^T : 16 rows x 32 cols per wave
        f32x4 accS[2];
        accS[0] = fzero;
        accS[1] = fzero;
        __builtin_amdgcn_s_setprio(1);
#pragma unroll
        for (int kc = 0; kc < 8; ++kc)
#pragma unroll
            for (int jt = 0; jt < 2; ++jt) {
                const int r = ch * 32 + jt * 16 + l15;
                const f16x8 kf =
                    *(const f16x8*)&Klds[cur][r * 256 + (((kc * 4 + quad) ^ (r & 7)) * 8)];
                accS[jt] = MFMA(qh[kc], kf, accS[jt]);
                accS[jt] = MFMA(qlt[kc], kf, accS[jt]);
            }
        __builtin_amdgcn_s_setprio(0);

        // phase 1: mask + per-wave partial row max (DPP, VALU pipe)
        float mymx[4];
#pragma unroll
        for (int rgi = 0; rgi < 4; ++rgi) {
            const int gr = growb + rgi;
            float mx = -3.0e38f;
#pragma unroll
            for (int jt = 0; jt < 2; ++jt) {
                const int gc = j0 + ch * 32 + jt * 16 + l15;
                const float s = (av[rgi][jt] != 0 || gr == gc) ? accS[jt][rgi] : -3.0e38f;
                accS[jt][rgi] = s;
                mx = fmaxf(mx, s);
            }
            mx = dpp_max16(mx);
            mymx[rgi] = mx;
            if (l15 == 0) pmaxLds[rg][ch][quad * 4 + rgi] = mx;
        }
        __syncthreads();  // pmax exchange (also drains stage loads)

        // phase 2: full row max, exact defer-rescale, exp, P write.
        // Both waves of the pair compute identical mrow -> consistent state.
#pragma unroll
        for (int rgi = 0; rgi < 4; ++rgi) {
            const float other = pmaxLds[rg][ch ^ 1][quad * 4 + rgi];
            const float mxf = fmaxf(mymx[rgi], other);
            const float mnew = fmaxf(mrow[rgi], mxf);
            if (__any(mnew > mrow[rgi])) {
                const float al = __expf(mrow[rgi] - mnew);
                mrow[rgi] = mnew;
                lpart[rgi] *= al;
#pragma unroll
                for (int nt = 0; nt < 8; ++nt) accO[nt][rgi] *= al;
            }
            float rs = 0.f;
            const int row = quad * 4 + rgi;
#pragma unroll
            for (int jt = 0; jt < 2; ++jt) {
                const float s = accS[jt][rgi];
                const float e = (s > -1.0e37f) ? __expf(s - mrow[rgi]) : 0.f;
                rs += e;
                Pw[row * PSTR + ch * 32 + jt * 16 + l15] = (f16)e;
            }
            lpart[rgi] += rs;  // per-lane partial over own half; epilogue combines
        }
        __syncthreads();  // P (both halves) visible

        // PV: 16 rows x 128 n per wave, full 64-k P strip of this row group
        f16x8 pf[2];
        pf[0] = *(const f16x8*)&Pw[l15 * PSTR + quad * 8];
        pf[1] = *(const f16x8*)&Pw[l15 * PSTR + 32 + quad * 8];
        __builtin_amdgcn_s_setprio(1);
#pragma unroll
        for (int nt = 0; nt < 8; ++nt)
#pragma unroll
            for (int kc2 = 0; kc2 < 2; ++kc2) {
                const int n = ch * 128 + nt * 16 + l15;
                const f16x8 vf =
                    *(const f16x8*)&Vlds[cur][n * 64 + (((kc2 * 4 + quad) ^ (n & 7)) * 8)];
                accO[nt] = MFMA(pf[kc2], vf, accO[nt]);
            }
        __builtin_amdgcn_s_setprio(0);

        // end barrier: compute(it) done before dbuf overwrite next iter
        __syncthreads();
    }

    // epilogue: reduce per-lane l partials (DPP), combine across ch pair via LDS
#pragma unroll
    for (int rgi = 0; rgi < 4; ++rgi) lpart[rgi] = dpp_sum16(lpart[rgi]);
    if (l15 == 0)
#pragma unroll
        for (int rgi = 0; rgi < 4; ++rgi) pmaxLds[rg][ch][quad * 4 + rgi] = lpart[rgi];
    __syncthreads();

    // write partials
#pragma unroll
    for (int nt = 0; nt < 8; ++nt)
#pragma unroll
        for (int rgi = 0; rgi < 4; ++rgi)
            pO[((size_t)cch * NN + growb + rgi) * DD + ch * 128 + nt * 16 + l15] =
                accO[nt][rgi];
    if (ch == 0 && l15 == 0) {
#pragma unroll
        for (int rgi = 0; rgi < 4; ++rgi) {
            pM[(size_t)cch * NN + growb + rgi] = mrow[rgi];
            pL[(size_t)cch * NN + growb + rgi] =
                pmaxLds[rg][0][quad * 4 + rgi] + pmaxLds[rg][1][quad * 4 + rgi];
        }
    }
}

// ---------------- merge partials (8 rows/block) ----------------
__global__ __launch_bounds__(256) void merge_kernel(const float* __restrict__ pO,
                                                    const float* __restrict__ pM,
                                                    const float* __restrict__ pL,
                                                    float* __restrict__ out) {
    const int n = threadIdx.x;
#pragma unroll 1
    for (int rr = 0; rr < 8; ++rr) {
        const int row = blockIdx.x * 8 + rr;
        float mc[CCH], lc[CCH];
        float M = -3e38f;
#pragma unroll
        for (int c = 0; c < CCH; ++c) {
            mc[c] = pM[(size_t)c * NN + row];
            lc[c] = pL[(size_t)c * NN + row];
            M = fmaxf(M, mc[c]);
        }
        float L = 0.f, acc = 0.f;
#pragma unroll
        for (int c = 0; c < CCH; ++c) {
            const float wgt = __expf(mc[c] - M);
            L += wgt * lc[c];
            acc += wgt * pO[((size_t)c * NN + row) * DD + n];
        }
        out[(size_t)row * DD + n] = acc / L;
    }
}

extern "C" void kernel_launch(void* const* d_in, const int* in_sizes, int n_in,
                              void* d_out, int out_size, void* d_ws, size_t ws_size,
                              hipStream_t stream) {
    const float* X = (const float*)d_in[0];
    const int* A = (const int*)d_in[1];
    const float* Wq = (const float*)d_in[2];
    const float* Wk = (const float*)d_in[3];
    const float* Wv = (const float*)d_in[4];
    float* out = (float*)d_out;

    char* ws = (char*)d_ws;
    const size_t MB = 1ull << 20;
    f16* Xh = (f16*)(ws + 0 * MB);
    f16* Xl = (f16*)(ws + 4 * MB);
    f16* WtH = (f16*)(ws + 8 * MB);
    f16* WtL = (f16*)(ws + 8 * MB + 512 * 1024);
    f16* Qh = (f16*)(ws + 9 * MB);
    f16* Ql = (f16*)(ws + 13 * MB);
    f16* Kh = (f16*)(ws + 17 * MB);
    f16* Vt = (f16*)(ws + 21 * MB);
    float* pO = (float*)(ws + 25 * MB);
    float* pM = (float*)(ws + 57 * MB);
    float* pL = (float*)(ws + 57 * MB + 256 * 1024);
    (void)ws_size; (void)in_sizes; (void)n_in; (void)out_size;

    prep_kernel<<<2816, 256, 0, stream>>>((const float4*)X, (f16x4*)Xh, (f16x4*)Xl,
                                          Wq, Wk, Wv, WtH, WtL);
    qkv_kernel<<<dim3(NN / 64, 3), 256, 0, stream>>>(Xh, Xl, WtH, WtL, Qh, Ql, Kh, Vt);
    flash_kernel<<<(NN / BR) * CCH, 1024, 0, stream>>>(Qh, Ql, Kh, Vt, A, pO, pM, pL);
    merge_kernel<<<NN / 8, 256, 0, stream>>>(pO, pM, pL, out);
}